// Round 5
// baseline (498.431 us; speedup 1.0000x reference)
//
#include <hip/hip_runtime.h>
#include <hip/hip_bf16.h>
#include <stdint.h>

typedef __bf16 bf16x8 __attribute__((ext_vector_type(8)));
typedef float  f32x4  __attribute__((ext_vector_type(4)));

#define SEQ   2048
#define DIMV  1024
#define HEADS 16
#define HDIM  64
#define KD    1024

// 0.125 (HEAD_DIM^-0.5) * log2(e)
#define SCL 0.1803368801111204f
// defer-max threshold in raw-score units: THR*SCL = 8 -> P <= 2^8
#define THRRAW 44.36f

static __device__ __forceinline__ unsigned short f2bf(float f) {
  union { float f; unsigned u; } v; v.f = f;
  unsigned r = (v.u + 0x7fffu + ((v.u >> 16) & 1u)) >> 16;
  return (unsigned short)r;
}

static __device__ __forceinline__ unsigned cvtpk(float a, float b) {
  unsigned r;
  asm("v_cvt_pk_bf16_f32 %0, %1, %2" : "=v"(r) : "v"(a), "v"(b));
  return r;  // low16 = bf16(a), high16 = bf16(b)
}

// ---------------- fp32 -> bf16 convert (vectorized) ----------------
__global__ void cvt_kernel(const float* __restrict__ src,
                           ushort4* __restrict__ dst, int n4) {
  int i = blockIdx.x * 256 + threadIdx.x;
  if (i >= n4) return;
  float4 v = reinterpret_cast<const float4*>(src)[i];
  ushort4 o;
  o.x = f2bf(v.x); o.y = f2bf(v.y); o.z = f2bf(v.z); o.w = f2bf(v.w);
  dst[i] = o;
}

// ---------------- async global->LDS 16B ----------------
static __device__ __forceinline__ void gload_lds16(const unsigned short* g,
                                                   unsigned short* l) {
  __builtin_amdgcn_global_load_lds(
      (const __attribute__((address_space(1))) unsigned int*)g,
      (__attribute__((address_space(3))) unsigned int*)l, 16, 0, 0);
}

// ---------------- GEMM: C[M,N] = A[M,K] * B[N,K]^T ----------------
template <int MODE>
__global__ __launch_bounds__(256) void gemm_bt(
    const unsigned short* __restrict__ A,
    const unsigned short* __restrict__ B,
    void* __restrict__ Cv,
    const float* __restrict__ bias) {
  __shared__ unsigned short As[128 * 32];
  __shared__ unsigned short Bs[128 * 32];
  const int t = threadIdx.x;
  const int lane = t & 63, wave = t >> 6;
  const int fr = lane & 15, fq = lane >> 4;
  const int m0 = blockIdx.x * 128, n0 = blockIdx.y * 128;
  const int wm0 = (wave >> 1) * 64, wn0 = (wave & 1) * 64;

  const int srow = wave * 16 + (lane >> 2);
  const int scol = (lane & 3) * 8;
  const unsigned short* gA = A + (size_t)(m0 + srow) * KD + scol;
  const unsigned short* gB = B + (size_t)(n0 + srow) * KD + scol;
  unsigned short* lA = &As[srow * 32 + scol];
  unsigned short* lB = &Bs[srow * 32 + scol];

  f32x4 acc[4][4];
#pragma unroll
  for (int i = 0; i < 4; ++i)
#pragma unroll
    for (int j = 0; j < 4; ++j) acc[i][j] = (f32x4){0.f, 0.f, 0.f, 0.f};

  for (int k0 = 0;;) {
    gload_lds16(gA + k0, lA);
    gload_lds16(gA + (size_t)64 * KD + k0, lA + 64 * 32);
    gload_lds16(gB + k0, lB);
    gload_lds16(gB + (size_t)64 * KD + k0, lB + 64 * 32);
    __syncthreads();

    bf16x8 af[4], bfv[4];
#pragma unroll
    for (int mi = 0; mi < 4; ++mi)
      af[mi] = *(const bf16x8*)&As[(wm0 + mi * 16 + fr) * 32 + fq * 8];
#pragma unroll
    for (int nj = 0; nj < 4; ++nj)
      bfv[nj] = *(const bf16x8*)&Bs[(wn0 + nj * 16 + fr) * 32 + fq * 8];
#pragma unroll
    for (int mi = 0; mi < 4; ++mi)
#pragma unroll
      for (int nj = 0; nj < 4; ++nj)
        acc[mi][nj] = __builtin_amdgcn_mfma_f32_16x16x32_bf16(
            af[mi], bfv[nj], acc[mi][nj], 0, 0, 0);

    k0 += 32;
    if (k0 >= KD) break;
    __syncthreads();
  }

#pragma unroll
  for (int mi = 0; mi < 4; ++mi)
#pragma unroll
    for (int nj = 0; nj < 4; ++nj)
#pragma unroll
      for (int r = 0; r < 4; ++r) {
        const int gr = m0 + wm0 + mi * 16 + fq * 4 + r;
        const int gc = n0 + wn0 + nj * 16 + fr;
        const float v = acc[mi][nj][r];
        if (MODE == 0) {
          size_t off = (((size_t)(gr >> 11) * HEADS + (gc >> 6)) * SEQ +
                        (gr & 2047)) * HDIM + (gc & 63);
          ((unsigned short*)Cv)[off] = f2bf(v);
        } else if (MODE == 1) {
          size_t off = (size_t)(gc >> 11) * (DIMV * SEQ) + (size_t)gr * SEQ +
                       (gc & 2047);
          ((unsigned short*)Cv)[off] = f2bf(v);
        } else {
          ((float*)Cv)[(size_t)gr * DIMV + gc] = v + bias[gc];
        }
      }
}

// ---------------- flash attention (LDS-staged K, dbuf; XCD-local bh) ------
// grid 2048 (1D): xcd = wg&7 owns 8 bh values (all 32 q-tiles) -> K/V L2-local.
// block = 4 waves x 16 q-rows = 64 rows.
// Swapped QK^T: lane holds S[q=fr][k=nj*16+fq*4+r] -> lane-local softmax.
// Swapped PV:   lane holds O[d=dj*16+fq*4+r][q=fr] -> lane-local rescale/norm.
__global__ __launch_bounds__(256, 4) void attn_kernel(
    const unsigned short* __restrict__ q, const unsigned short* __restrict__ k,
    const unsigned short* __restrict__ vt, unsigned short* __restrict__ ao) {
  __shared__ unsigned short Ks[2][64 * 64];  // K tile dbuf, XOR-swizzled rows
  __shared__ unsigned short Pl[4][16 * 64];  // per-wave P, XOR-swizzled
  const int t = threadIdx.x, lane = t & 63, wave = t >> 6;
  const int fr = lane & 15, fq = lane >> 4;
  const int wg = blockIdx.x;
  const int xcd = wg & 7, idx = wg >> 3;
  const int bh = (xcd << 3) | (idx >> 5);   // 8 bh per XCD
  const int qt = idx & 31;
  const int b = bh >> 4, h = bh & 15;
  const int qrow0 = qt * 64 + wave * 16;

  const unsigned short* qp = q + ((size_t)bh * SEQ + qrow0) * HDIM;
  const unsigned short* kp = k + (size_t)bh * SEQ * HDIM;
  const unsigned short* vp = vt + (size_t)b * (DIMV * SEQ) + (size_t)(h * HDIM) * SEQ;
  char* plw = (char*)&Pl[wave][0];

  // staging coords: thread t covers LDS bytes [i*4096 + t*16) per issue i.
  // LDS(rb, cb) holds global K(kb+rb, cb ^ ((rb&7)<<4))  (pre-swizzled source)
  const int rb = t >> 3;           // +32 on second issue
  const int cb = (t & 7) << 4;     // byte col

  bf16x8 qf[2];
#pragma unroll
  for (int kc = 0; kc < 2; ++kc)
    qf[kc] = *(const bf16x8*)(qp + (size_t)fr * HDIM + kc * 32 + fq * 8);

  f32x4 oacc[4];
#pragma unroll
  for (int dj = 0; dj < 4; ++dj) oacc[dj] = (f32x4){0.f, 0.f, 0.f, 0.f};
  float m_s = -1e30f, lrow = 0.f;

  // prologue: stage tile 0
#pragma unroll
  for (int i = 0; i < 2; ++i) {
    const int r = rb + i * 32;
    gload_lds16(kp + (size_t)r * HDIM + ((cb ^ ((r & 7) << 4)) >> 1),
                (unsigned short*)((char*)&Ks[0][0] + i * 4096 + t * 16));
  }
  __syncthreads();

  int cur = 0;
  for (int kb = 0; kb < SEQ; kb += 64, cur ^= 1) {
    // stage next K tile into the other buffer (drained by end-of-iter barrier)
    if (kb + 64 < SEQ) {
#pragma unroll
      for (int i = 0; i < 2; ++i) {
        const int r = rb + i * 32;
        gload_lds16(kp + (size_t)(kb + 64 + r) * HDIM + ((cb ^ ((r & 7) << 4)) >> 1),
                    (unsigned short*)((char*)&Ks[cur ^ 1][0] + i * 4096 + t * 16));
      }
    }
    // V register loads (cover = QK + softmax)
    bf16x8 vf[4][2];
#pragma unroll
    for (int dj = 0; dj < 4; ++dj)
#pragma unroll
      for (int kc = 0; kc < 2; ++kc)
        vf[dj][kc] = *(const bf16x8*)(vp + (size_t)(dj * 16 + fr) * SEQ + kb + kc * 32 + fq * 8);

    // ---- S = mfma(K, Q) from LDS ----
    const char* kls = (const char*)&Ks[cur][0];
    f32x4 sacc[4];
#pragma unroll
    for (int nj = 0; nj < 4; ++nj) sacc[nj] = (f32x4){0.f, 0.f, 0.f, 0.f};
#pragma unroll
    for (int kc = 0; kc < 2; ++kc) {
      bf16x8 kf[4];
#pragma unroll
      for (int nj = 0; nj < 4; ++nj)
        kf[nj] = *(const bf16x8*)(kls + (nj * 16 + fr) * 128 +
                                  ((kc * 64 + fq * 16) ^ ((fr & 7) << 4)));
      __builtin_amdgcn_s_setprio(1);
#pragma unroll
      for (int nj = 0; nj < 4; ++nj)
        sacc[nj] = __builtin_amdgcn_mfma_f32_16x16x32_bf16(
            kf[nj], qf[kc], sacc[nj], 0, 0, 0);
      __builtin_amdgcn_s_setprio(0);
    }

    // ---- softmax, lane-local per q-row (q = fr) ----
    float t0 = fmaxf(fmaxf(sacc[0][0], sacc[0][1]), fmaxf(sacc[0][2], sacc[0][3]));
    float t1 = fmaxf(fmaxf(sacc[1][0], sacc[1][1]), fmaxf(sacc[1][2], sacc[1][3]));
    float t2 = fmaxf(fmaxf(sacc[2][0], sacc[2][1]), fmaxf(sacc[2][2], sacc[2][3]));
    float t3 = fmaxf(fmaxf(sacc[3][0], sacc[3][1]), fmaxf(sacc[3][2], sacc[3][3]));
    float tmax = fmaxf(fmaxf(t0, t1), fmaxf(t2, t3));
    tmax = fmaxf(tmax, __shfl_xor(tmax, 16));
    tmax = fmaxf(tmax, __shfl_xor(tmax, 32));

    if (__any(tmax > m_s + THRRAW)) {  // T13 defer-max
      const float mnew = fmaxf(m_s, tmax);
      const float fo = exp2f((m_s - mnew) * SCL);
      m_s = mnew;
      lrow *= fo;
#pragma unroll
      for (int dj = 0; dj < 4; ++dj)
#pragma unroll
        for (int r = 0; r < 4; ++r) oacc[dj][r] *= fo;
    }

    const float nm = m_s * SCL;
    float lacc = 0.f;
#pragma unroll
    for (int nj = 0; nj < 4; ++nj) {
      float p0 = exp2f(__builtin_fmaf(sacc[nj][0], SCL, -nm));
      float p1 = exp2f(__builtin_fmaf(sacc[nj][1], SCL, -nm));
      float p2 = exp2f(__builtin_fmaf(sacc[nj][2], SCL, -nm));
      float p3 = exp2f(__builtin_fmaf(sacc[nj][3], SCL, -nm));
      lacc += (p0 + p1) + (p2 + p3);
      unsigned w0 = cvtpk(p0, p1);
      unsigned w1 = cvtpk(p2, p3);
      const int colb = (nj * 16 + fq * 4) * 2;
      *(uint2*)(plw + ((fr * 128 + colb) ^ ((fr & 7) << 4))) = make_uint2(w0, w1);
    }
    lrow += lacc;

    // ---- O += mfma(V, P) ----
#pragma unroll
    for (int kc = 0; kc < 2; ++kc) {
      bf16x8 pf = *(const bf16x8*)(plw + ((fr * 128 + kc * 64 + fq * 16) ^ ((fr & 7) << 4)));
      __builtin_amdgcn_s_setprio(1);
#pragma unroll
      for (int dj = 0; dj < 4; ++dj)
        oacc[dj] = __builtin_amdgcn_mfma_f32_16x16x32_bf16(
            vf[dj][kc], pf, oacc[dj], 0, 0, 0);
      __builtin_amdgcn_s_setprio(0);
    }

    __syncthreads();  // stage(t+1) drained; all reads of Ks[cur] done
  }

  // ---- final: l reduce across fq groups, lane-local normalize, store ----
  float lt = lrow;
  lt += __shfl_xor(lt, 16);
  lt += __shfl_xor(lt, 32);
  const float inv = 1.f / lt;
  const size_t grow = (size_t)b * SEQ + qt * 64 + wave * 16 + fr;
#pragma unroll
  for (int dj = 0; dj < 4; ++dj) {
    unsigned w0 = cvtpk(oacc[dj][0] * inv, oacc[dj][1] * inv);
    unsigned w1 = cvtpk(oacc[dj][2] * inv, oacc[dj][3] * inv);
    const int col = h * HDIM + dj * 16 + fq * 4;
    *(uint2*)&ao[grow * DIMV + col] = make_uint2(w0, w1);
  }
}

// ---------------- launch ----------------
extern "C" void kernel_launch(void* const* d_in, const int* in_sizes, int n_in,
                              void* d_out, int out_size, void* d_ws, size_t ws_size,
                              hipStream_t stream) {
  const float* x   = (const float*)d_in[0];
  const float* ctx = (const float*)d_in[1];
  const float* Wq  = (const float*)d_in[2];
  const float* Wk  = (const float*)d_in[3];
  const float* Wv  = (const float*)d_in[4];
  const float* Wo  = (const float*)d_in[5];
  const float* bo  = (const float*)d_in[6];

  char* ws = (char*)d_ws;
  unsigned short* xb  = (unsigned short*)(ws);              // 16MB, reused as ao
  unsigned short* cb  = (unsigned short*)(ws + 16777216);   // 16MB
  unsigned short* wqb = (unsigned short*)(ws + 33554432);   // 2MB
  unsigned short* wkb = (unsigned short*)(ws + 35651584);
  unsigned short* wvb = (unsigned short*)(ws + 37748736);
  unsigned short* wob = (unsigned short*)(ws + 39845888);
  unsigned short* qb  = (unsigned short*)(ws + 41943040);   // 16MB
  unsigned short* kb  = (unsigned short*)(ws + 58720256);   // 16MB
  unsigned short* vtb = (unsigned short*)(ws + 75497472);   // 16MB

  auto cvt = [&](const float* s, unsigned short* d, int n) {
    int n4 = n >> 2;
    cvt_kernel<<<(n4 + 255) / 256, 256, 0, stream>>>(s, (ushort4*)d, n4);
  };
  const int NTOK = 4 * SEQ;  // 8192
  cvt(x,   xb,  NTOK * DIMV);
  cvt(ctx, cb,  NTOK * DIMV);
  cvt(Wq,  wqb, DIMV * DIMV);
  cvt(Wk,  wkb, DIMV * DIMV);
  cvt(Wv,  wvb, DIMV * DIMV);
  cvt(Wo,  wob, DIMV * DIMV);

  gemm_bt<0><<<dim3(64, 8), 256, 0, stream>>>(xb, wqb, qb, nullptr);
  gemm_bt<0><<<dim3(64, 8), 256, 0, stream>>>(cb, wkb, kb, nullptr);
  gemm_bt<1><<<dim3(8, 64), 256, 0, stream>>>(wvb, cb, vtb, nullptr);

  unsigned short* aob = xb;
  attn_kernel<<<dim3(2048), 256, 0, stream>>>(qb, kb, vtb, aob);

  gemm_bt<2><<<dim3(64, 8), 256, 0, stream>>>(aob, wob, (float*)d_out, bo);
}

// Round 6
// 473.002 us; speedup vs baseline: 1.0538x; 1.0538x over previous
//
#include <hip/hip_runtime.h>
#include <hip/hip_bf16.h>
#include <stdint.h>

typedef __bf16 bf16x8 __attribute__((ext_vector_type(8)));
typedef float  f32x4  __attribute__((ext_vector_type(4)));

#define SEQ   2048
#define DIMV  1024
#define HEADS 16
#define HDIM  64
#define KD    1024

// 0.125 (HEAD_DIM^-0.5) * log2(e)
#define SCL 0.1803368801111204f
// defer-max threshold in raw-score units: THRRAW*SCL = 8 -> P <= 2^8
#define THRRAW 44.36f

static __device__ __forceinline__ unsigned short f2bf(float f) {
  union { float f; unsigned u; } v; v.f = f;
  unsigned r = (v.u + 0x7fffu + ((v.u >> 16) & 1u)) >> 16;
  return (unsigned short)r;
}

// ---------------- fp32 -> bf16 convert (vectorized) ----------------
__global__ void cvt_kernel(const float* __restrict__ src,
                           ushort4* __restrict__ dst, int n4) {
  int i = blockIdx.x * 256 + threadIdx.x;
  if (i >= n4) return;
  float4 v = reinterpret_cast<const float4*>(src)[i];
  ushort4 o;
  o.x = f2bf(v.x); o.y = f2bf(v.y); o.z = f2bf(v.z); o.w = f2bf(v.w);
  dst[i] = o;
}

// ---------------- async global->LDS 16B ----------------
static __device__ __forceinline__ void gload_lds16(const unsigned short* g,
                                                   unsigned short* l) {
  __builtin_amdgcn_global_load_lds(
      (const __attribute__((address_space(1))) unsigned int*)g,
      (__attribute__((address_space(3))) unsigned int*)l, 16, 0, 0);
}

// ---------------- GEMM: C[M,N] = A[M,K] * B[N,K]^T ----------------
template <int MODE>
__global__ __launch_bounds__(256) void gemm_bt(
    const unsigned short* __restrict__ A,
    const unsigned short* __restrict__ B,
    void* __restrict__ Cv,
    const float* __restrict__ bias) {
  __shared__ unsigned short As[128 * 32];
  __shared__ unsigned short Bs[128 * 32];
  const int t = threadIdx.x;
  const int lane = t & 63, wave = t >> 6;
  const int fr = lane & 15, fq = lane >> 4;
  const int m0 = blockIdx.x * 128, n0 = blockIdx.y * 128;
  const int wm0 = (wave >> 1) * 64, wn0 = (wave & 1) * 64;

  const int srow = wave * 16 + (lane >> 2);
  const int scol = (lane & 3) * 8;
  const unsigned short* gA = A + (size_t)(m0 + srow) * KD + scol;
  const unsigned short* gB = B + (size_t)(n0 + srow) * KD + scol;
  unsigned short* lA = &As[srow * 32 + scol];
  unsigned short* lB = &Bs[srow * 32 + scol];

  f32x4 acc[4][4];
#pragma unroll
  for (int i = 0; i < 4; ++i)
#pragma unroll
    for (int j = 0; j < 4; ++j) acc[i][j] = (f32x4){0.f, 0.f, 0.f, 0.f};

  for (int k0 = 0;;) {
    gload_lds16(gA + k0, lA);
    gload_lds16(gA + (size_t)64 * KD + k0, lA + 64 * 32);
    gload_lds16(gB + k0, lB);
    gload_lds16(gB + (size_t)64 * KD + k0, lB + 64 * 32);
    __syncthreads();

    bf16x8 af[4], bfv[4];
#pragma unroll
    for (int mi = 0; mi < 4; ++mi)
      af[mi] = *(const bf16x8*)&As[(wm0 + mi * 16 + fr) * 32 + fq * 8];
#pragma unroll
    for (int nj = 0; nj < 4; ++nj)
      bfv[nj] = *(const bf16x8*)&Bs[(wn0 + nj * 16 + fr) * 32 + fq * 8];
#pragma unroll
    for (int mi = 0; mi < 4; ++mi)
#pragma unroll
      for (int nj = 0; nj < 4; ++nj)
        acc[mi][nj] = __builtin_amdgcn_mfma_f32_16x16x32_bf16(
            af[mi], bfv[nj], acc[mi][nj], 0, 0, 0);

    k0 += 32;
    if (k0 >= KD) break;
    __syncthreads();
  }

#pragma unroll
  for (int mi = 0; mi < 4; ++mi)
#pragma unroll
    for (int nj = 0; nj < 4; ++nj)
#pragma unroll
      for (int r = 0; r < 4; ++r) {
        const int gr = m0 + wm0 + mi * 16 + fq * 4 + r;
        const int gc = n0 + wn0 + nj * 16 + fr;
        const float v = acc[mi][nj][r];
        if (MODE == 0) {
          size_t off = (((size_t)(gr >> 11) * HEADS + (gc >> 6)) * SEQ +
                        (gr & 2047)) * HDIM + (gc & 63);
          ((unsigned short*)Cv)[off] = f2bf(v);
        } else if (MODE == 1) {
          size_t off = (size_t)(gc >> 11) * (DIMV * SEQ) + (size_t)gr * SEQ +
                       (gc & 2047);
          ((unsigned short*)Cv)[off] = f2bf(v);
        } else {
          ((float*)Cv)[(size_t)gr * DIMV + gc] = v + bias[gc];
        }
      }
}

// ---------------- flash attention (R3 structure + XCD-local bh) ----------
// grid 1024 (1D): xcd = wg&7 owns 8 bh (all 16 q-tiles) -> K/V = 4MB, L2-fit.
// 4 waves x 32 q-rows. Swapped QK^T: lane holds S[q=fr(+16mi)][k=nj*16+fq*4+r]
// -> lane-local softmax. PV = mfma(P, V): O[q=fq*4+r][d=fr].
__global__ __launch_bounds__(256) void attn_kernel(
    const unsigned short* __restrict__ q, const unsigned short* __restrict__ k,
    const unsigned short* __restrict__ vt, unsigned short* __restrict__ ao) {
  __shared__ unsigned short Pl[4][32 * 64];  // per-wave P tile, XOR-swizzled
  const int t = threadIdx.x, lane = t & 63, wave = t >> 6;
  const int fr = lane & 15, fq = lane >> 4;
  const int wg = blockIdx.x;
  const int xcd = wg & 7, idx = wg >> 3;
  const int bh = (xcd << 3) | (idx >> 4);   // 8 bh per XCD
  const int qt = idx & 15;
  const int b = bh >> 4, h = bh & 15;
  const int qrow0 = qt * 128 + wave * 32;

  const unsigned short* qp = q + ((size_t)bh * SEQ + qrow0) * HDIM;
  const unsigned short* kp = k + (size_t)bh * SEQ * HDIM;
  const unsigned short* vp = vt + (size_t)b * (DIMV * SEQ) + (size_t)(h * HDIM) * SEQ;
  char* plw = (char*)&Pl[wave][0];

  bf16x8 qf[2][2];
#pragma unroll
  for (int mi = 0; mi < 2; ++mi)
#pragma unroll
    for (int kc = 0; kc < 2; ++kc)
      qf[mi][kc] = *(const bf16x8*)(qp + (size_t)(mi * 16 + fr) * HDIM + kc * 32 + fq * 8);

  f32x4 oacc[2][4];
  float m_s[2], m_o[2][4], lrow[2];
#pragma unroll
  for (int mi = 0; mi < 2; ++mi) {
#pragma unroll
    for (int dj = 0; dj < 4; ++dj) oacc[mi][dj] = (f32x4){0.f, 0.f, 0.f, 0.f};
    m_s[mi] = -1e30f; lrow[mi] = 0.f;
#pragma unroll
    for (int r = 0; r < 4; ++r) m_o[mi][r] = -1e30f;
  }

  for (int kb = 0; kb < SEQ; kb += 64) {
    // ---- K and V register loads issued up front (L2-resident now) ----
    bf16x8 kf[4][2], vf[4][2];
#pragma unroll
    for (int nj = 0; nj < 4; ++nj)
#pragma unroll
      for (int kc = 0; kc < 2; ++kc)
        kf[nj][kc] = *(const bf16x8*)(kp + (size_t)(kb + nj * 16 + fr) * HDIM + kc * 32 + fq * 8);
#pragma unroll
    for (int dj = 0; dj < 4; ++dj)
#pragma unroll
      for (int kc = 0; kc < 2; ++kc)
        vf[dj][kc] = *(const bf16x8*)(vp + (size_t)(dj * 16 + fr) * SEQ + kb + kc * 32 + fq * 8);

    // ---- S = mfma(K, Q): lane holds S[q=mi*16+fr][k=nj*16+fq*4+r] ----
    f32x4 sacc[2][4];
#pragma unroll
    for (int mi = 0; mi < 2; ++mi)
#pragma unroll
      for (int nj = 0; nj < 4; ++nj) sacc[mi][nj] = (f32x4){0.f, 0.f, 0.f, 0.f};
    __builtin_amdgcn_s_setprio(1);
#pragma unroll
    for (int mi = 0; mi < 2; ++mi)
#pragma unroll
      for (int nj = 0; nj < 4; ++nj)
#pragma unroll
        for (int kc = 0; kc < 2; ++kc)
          sacc[mi][nj] = __builtin_amdgcn_mfma_f32_16x16x32_bf16(
              kf[nj][kc], qf[mi][kc], sacc[mi][nj], 0, 0, 0);
    __builtin_amdgcn_s_setprio(0);

    // ---- online softmax: lane-local per q-row ----
#pragma unroll
    for (int mi = 0; mi < 2; ++mi) {
      float tmax = -1e30f;
#pragma unroll
      for (int nj = 0; nj < 4; ++nj)
#pragma unroll
        for (int r = 0; r < 4; ++r) tmax = fmaxf(tmax, sacc[mi][nj][r]);
      tmax = fmaxf(tmax, __shfl_xor(tmax, 16));
      tmax = fmaxf(tmax, __shfl_xor(tmax, 32));

      if (__any(tmax > m_s[mi] + THRRAW)) {   // defer-max (T13)
        const float mnew = fmaxf(m_s[mi], tmax);
        lrow[mi] *= exp2f((m_s[mi] - mnew) * SCL);
        m_s[mi] = mnew;
#pragma unroll
        for (int r = 0; r < 4; ++r) {
          const float t_o = __shfl(tmax, ((lane >> 4) << 2) + r);
          const float mo_new = fmaxf(m_o[mi][r], t_o);
          const float fo = exp2f((m_o[mi][r] - mo_new) * SCL);
          m_o[mi][r] = mo_new;
#pragma unroll
          for (int dj = 0; dj < 4; ++dj) oacc[mi][dj][r] *= fo;
        }
      }

      const float nm = m_s[mi] * SCL;
      float ls = 0.f;
      const int row = mi * 16 + fr;
#pragma unroll
      for (int nj = 0; nj < 4; ++nj) {
        float p0 = exp2f(__builtin_fmaf(sacc[mi][nj][0], SCL, -nm));
        float p1 = exp2f(__builtin_fmaf(sacc[mi][nj][1], SCL, -nm));
        float p2 = exp2f(__builtin_fmaf(sacc[mi][nj][2], SCL, -nm));
        float p3 = exp2f(__builtin_fmaf(sacc[mi][nj][3], SCL, -nm));
        ls += (p0 + p1) + (p2 + p3);
        unsigned lo = (unsigned)f2bf(p0) | ((unsigned)f2bf(p1) << 16);
        unsigned hi = (unsigned)f2bf(p2) | ((unsigned)f2bf(p3) << 16);
        const int colb = (nj * 16 + fq * 4) * 2;
        *(uint2*)(plw + ((row * 128 + colb) ^ ((row & 7) << 4))) =
            make_uint2(lo, hi);
      }
      lrow[mi] += ls;
    }

    // ---- O += mfma(P, V): O[q=fq*4+r][d=fr] ----
    bf16x8 pf[2][2];
#pragma unroll
    for (int mi = 0; mi < 2; ++mi)
#pragma unroll
      for (int kc = 0; kc < 2; ++kc) {
        const int row = mi * 16 + fr, colb = (kc * 32 + fq * 8) * 2;
        pf[mi][kc] = *(const bf16x8*)(plw + ((row * 128 + colb) ^ ((row & 7) << 4)));
      }
    __builtin_amdgcn_s_setprio(1);
#pragma unroll
    for (int mi = 0; mi < 2; ++mi)
#pragma unroll
      for (int dj = 0; dj < 4; ++dj)
#pragma unroll
        for (int kc = 0; kc < 2; ++kc)
          oacc[mi][dj] = __builtin_amdgcn_mfma_f32_16x16x32_bf16(
              pf[mi][kc], vf[dj][kc], oacc[mi][dj], 0, 0, 0);
    __builtin_amdgcn_s_setprio(0);
  }

  // ---- final l reduce + redistribute to O-layout, normalize + store ----
#pragma unroll
  for (int mi = 0; mi < 2; ++mi) {
    float lt = lrow[mi];
    lt += __shfl_xor(lt, 16);
    lt += __shfl_xor(lt, 32);
#pragma unroll
    for (int r = 0; r < 4; ++r) {
      const float l_o = __shfl(lt, ((lane >> 4) << 2) + r);
      const float inv = 1.f / l_o;
      const size_t grow = (size_t)b * SEQ + qt * 128 + wave * 32 +
                          mi * 16 + fq * 4 + r;
#pragma unroll
      for (int dj = 0; dj < 4; ++dj) {
        const int col = h * HDIM + dj * 16 + fr;
        ao[grow * DIMV + col] = f2bf(oacc[mi][dj][r] * inv);
      }
    }
  }
}

// ---------------- launch ----------------
extern "C" void kernel_launch(void* const* d_in, const int* in_sizes, int n_in,
                              void* d_out, int out_size, void* d_ws, size_t ws_size,
                              hipStream_t stream) {
  const float* x   = (const float*)d_in[0];
  const float* ctx = (const float*)d_in[1];
  const float* Wq  = (const float*)d_in[2];
  const float* Wk  = (const float*)d_in[3];
  const float* Wv  = (const float*)d_in[4];
  const float* Wo  = (const float*)d_in[5];
  const float* bo  = (const float*)d_in[6];

  char* ws = (char*)d_ws;
  unsigned short* xb  = (unsigned short*)(ws);              // 16MB, reused as ao
  unsigned short* cb  = (unsigned short*)(ws + 16777216);   // 16MB
  unsigned short* wqb = (unsigned short*)(ws + 33554432);   // 2MB
  unsigned short* wkb = (unsigned short*)(ws + 35651584);
  unsigned short* wvb = (unsigned short*)(ws + 37748736);
  unsigned short* wob = (unsigned short*)(ws + 39845888);
  unsigned short* qb  = (unsigned short*)(ws + 41943040);   // 16MB
  unsigned short* kb  = (unsigned short*)(ws + 58720256);   // 16MB
  unsigned short* vtb = (unsigned short*)(ws + 75497472);   // 16MB

  auto cvt = [&](const float* s, unsigned short* d, int n) {
    int n4 = n >> 2;
    cvt_kernel<<<(n4 + 255) / 256, 256, 0, stream>>>(s, (ushort4*)d, n4);
  };
  const int NTOK = 4 * SEQ;  // 8192
  cvt(x,   xb,  NTOK * DIMV);
  cvt(ctx, cb,  NTOK * DIMV);
  cvt(Wq,  wqb, DIMV * DIMV);
  cvt(Wk,  wkb, DIMV * DIMV);
  cvt(Wv,  wvb, DIMV * DIMV);
  cvt(Wo,  wob, DIMV * DIMV);

  gemm_bt<0><<<dim3(64, 8), 256, 0, stream>>>(xb, wqb, qb, nullptr);
  gemm_bt<0><<<dim3(64, 8), 256, 0, stream>>>(cb, wkb, kb, nullptr);
  gemm_bt<1><<<dim3(8, 64), 256, 0, stream>>>(wvb, cb, vtb, nullptr);

  unsigned short* aob = xb;
  attn_kernel<<<dim3(1024), 256, 0, stream>>>(qb, kb, vtb, aob);

  gemm_bt<2><<<dim3(64, 8), 256, 0, stream>>>(aob, wob, (float*)d_out, bo);
}